// Round 15
// baseline (239.666 us; speedup 1.0000x reference)
//
#include <hip/hip_runtime.h>
#include <hip/hip_bf16.h>
#include <stdint.h>

typedef __bf16 bf16_t;
typedef __bf16 bf16x8 __attribute__((ext_vector_type(8)));
typedef float  f32x4  __attribute__((ext_vector_type(4)));

__device__ __forceinline__ void gload16(const void* gp, void* lp) {
  __builtin_amdgcn_global_load_lds(
      (const __attribute__((address_space(1))) void*)(uintptr_t)gp,
      (__attribute__((address_space(3))) void*)(uintptr_t)lp,
      16, 0, 0);
}

__device__ __forceinline__ f32x4 mfma16(bf16x8 a, bf16x8 b, f32x4 c) {
  return __builtin_amdgcn_mfma_f32_16x16x32_bf16(a, b, c, 0, 0, 0);
}

__device__ __forceinline__ uint32_t pack2(float a, float b) {
  uint16_t ba = __builtin_bit_cast(uint16_t, (bf16_t)a);
  uint16_t bb = __builtin_bit_cast(uint16_t, (bf16_t)b);
  return (uint32_t)ba | ((uint32_t)bb << 16);
}

// ---------------- fp32 -> bf16 cast (memory-bound, vectorized) ----------------
__global__ __launch_bounds__(256) void cast_f32_to_bf16(const float* __restrict__ in,
                                                        bf16_t* __restrict__ out, int n8) {
  int i = blockIdx.x * 256 + threadIdx.x;
  int stride = gridDim.x * 256;
  for (; i < n8; i += stride) {
    const f32x4* p = (const f32x4*)in + (size_t)i * 2;
    f32x4 a = p[0], b = p[1];
    bf16x8 o;
    o[0] = (bf16_t)a[0]; o[1] = (bf16_t)a[1]; o[2] = (bf16_t)a[2]; o[3] = (bf16_t)a[3];
    o[4] = (bf16_t)b[0]; o[5] = (bf16_t)b[1]; o[6] = (bf16_t)b[2]; o[7] = (bf16_t)b[3];
    ((bf16x8*)out)[i] = o;
  }
}

// ======== 256x384 GEMM + fused RoPE/scale epilogue (gemm1) — round-13 verified ========
// (Round-14 v2 reverted: depth-1 prefetch + vmcnt(0)/tile exposed HBM latency.)
__global__ __launch_bounds__(512, 2) void gemm_qkv(const bf16_t* __restrict__ A,
                                                   const bf16_t* __restrict__ B,
                                                   bf16_t* __restrict__ C,
                                                   int M, int N, int K) {
  __shared__ __align__(16) bf16_t As[2][256 * 32];
  __shared__ __align__(16) bf16_t Bs[2][384 * 32];
  const int t = threadIdx.x;
  const int wid = t >> 6, l = t & 63;
  const int l15 = l & 15, l4 = l >> 4;
  const int wm = wid >> 2, wn = wid & 3;
  const long m0 = (long)blockIdx.x * 256;
  const long n0 = (long)blockIdx.y * 384;
  const int KT = K >> 5;

  auto stageA = [&](int kt, bf16_t* __restrict__ LB) {
    #pragma unroll
    for (int it = 0; it < 2; ++it) {
      int s = it * 512 + t;
      int r = s >> 2, c = s & 3;
      int cs = c ^ ((r >> 1) & 3);
      gload16(A + (m0 + r) * (long)K + kt * 32 + cs * 8, LB + r * 32 + c * 8);
    }
  };
  auto stageB = [&](int kt, bf16_t* __restrict__ LB) {
    #pragma unroll
    for (int it = 0; it < 3; ++it) {
      int s = it * 512 + t;
      int r = s >> 2, c = s & 3;
      int cs = c ^ ((r >> 1) & 3);
      gload16(B + (n0 + r) * (long)K + kt * 32 + cs * 8, LB + r * 32 + c * 8);
    }
  };
  auto ldfrag = [&](const bf16_t* buf, int rloc) -> bf16x8 {
    int cs = l4 ^ ((rloc >> 1) & 3);
    return *(const bf16x8*)(buf + rloc * 32 + cs * 8);
  };

  f32x4 acc[8][6] = {};

  stageB(0, &Bs[0][0]);
  stageA(0, &As[0][0]);
  stageB(1, &Bs[1][0]);
  asm volatile("s_waitcnt vmcnt(3)" ::: "memory");
  asm volatile("s_barrier" ::: "memory");

  for (int kt = 0; kt < KT; ++kt) {
    const bf16_t* Ab = &As[kt & 1][0];
    const bf16_t* Bb = &Bs[kt & 1][0];
    const bool stA = (kt + 1 < KT), stB = (kt + 2 < KT);

    bf16x8 bfr[6];
    #pragma unroll
    for (int nr = 0; nr < 6; ++nr) bfr[nr] = ldfrag(Bb, wn * 96 + nr * 16 + l15);
    {
      bf16x8 a0 = ldfrag(Ab, wm * 128 + 0 * 16 + l15);
      bf16x8 a1 = ldfrag(Ab, wm * 128 + 1 * 16 + l15);
      bf16x8 a2 = ldfrag(Ab, wm * 128 + 2 * 16 + l15);
      bf16x8 a3 = ldfrag(Ab, wm * 128 + 3 * 16 + l15);
      if (stA) stageA(kt + 1, &As[(kt + 1) & 1][0]);
      asm volatile("s_barrier" ::: "memory");
      __builtin_amdgcn_s_setprio(1);
      #pragma unroll
      for (int nr = 0; nr < 6; ++nr) {
        acc[0][nr] = mfma16(a0, bfr[nr], acc[0][nr]);
        acc[1][nr] = mfma16(a1, bfr[nr], acc[1][nr]);
        acc[2][nr] = mfma16(a2, bfr[nr], acc[2][nr]);
        acc[3][nr] = mfma16(a3, bfr[nr], acc[3][nr]);
      }
      __builtin_amdgcn_s_setprio(0);
      asm volatile("s_barrier" ::: "memory");
    }
    {
      bf16x8 a4 = ldfrag(Ab, wm * 128 + 4 * 16 + l15);
      bf16x8 a5 = ldfrag(Ab, wm * 128 + 5 * 16 + l15);
      bf16x8 a6 = ldfrag(Ab, wm * 128 + 6 * 16 + l15);
      bf16x8 a7 = ldfrag(Ab, wm * 128 + 7 * 16 + l15);
      if (stB) stageB(kt + 2, &Bs[kt & 1][0]);
      asm volatile("s_barrier" ::: "memory");
      __builtin_amdgcn_s_setprio(1);
      #pragma unroll
      for (int nr = 0; nr < 6; ++nr) {
        acc[4][nr] = mfma16(a4, bfr[nr], acc[4][nr]);
        acc[5][nr] = mfma16(a5, bfr[nr], acc[5][nr]);
        acc[6][nr] = mfma16(a6, bfr[nr], acc[6][nr]);
        acc[7][nr] = mfma16(a7, bfr[nr], acc[7][nr]);
      }
      __builtin_amdgcn_s_setprio(0);
      if (stB) asm volatile("s_waitcnt vmcnt(3)" ::: "memory");
      else     asm volatile("s_waitcnt vmcnt(0)" ::: "memory");
      asm volatile("s_barrier" ::: "memory");
    }
  }

  // ---- epilogue: fused rope(rot_dim=32) + q-scale (rule #20: static acc idx) ----
  const int nrA = ((128 - ((wn * 96) & 127)) & 127) >> 4;
  const float L2D16 = 0.8304820237218406f;
  const float invf = exp2f(-(float)l15 * L2D16);
  const float qscale = 0.08838834764831845f;
  const float INV2PI = 0.15915494309189535f;
  const float TWOPI  = 6.283185307179586f;
  const bool doRot = (nrA < 6) && ((n0 + wn * 96 + nrA * 16) < 4096);
  #pragma unroll
  for (int mr = 0; mr < 8; ++mr) {
    const long r0 = m0 + wm * 128 + mr * 16 + l4 * 4;
    if (doRot) {
      float sv[4], cv[4];
      #pragma unroll
      for (int i = 0; i < 4; ++i) {
        float ang = (float)((int)(r0 + i) & 2047) * invf;
        float rev = ang * INV2PI;
        rev -= floorf(rev);
        float r2 = rev * TWOPI;
        sv[i] = __sinf(r2);
        cv[i] = __cosf(r2);
      }
      #pragma unroll
      for (int nr = 0; nr < 5; ++nr) {
        if (nr == nrA) {
          #pragma unroll
          for (int i = 0; i < 4; ++i) {
            float a = acc[mr][nr][i], b2 = acc[mr][nr + 1][i];
            acc[mr][nr][i]     = a * cv[i] - b2 * sv[i];
            acc[mr][nr + 1][i] = b2 * cv[i] + a * sv[i];
          }
        }
      }
    }
    #pragma unroll
    for (int nr = 0; nr < 6; ++nr) {
      const long f0 = n0 + wn * 96 + nr * 16;
      if (f0 < 2048) {
        #pragma unroll
        for (int i = 0; i < 4; ++i) acc[mr][nr][i] *= qscale;
      }
      #pragma unroll
      for (int i = 0; i < 4; ++i)
        C[(r0 + i) * N + f0 + l15] = (bf16_t)acc[mr][nr][i];
    }
  }
}

// ======== 128x256 GEMM (gemm2), round-13 structure ========
template<bool OUT_BF16>
__global__ __launch_bounds__(512, 2) void gemm8p_bt(const bf16_t* __restrict__ A,
                                                    const bf16_t* __restrict__ B,
                                                    void* __restrict__ Cout,
                                                    int M, int N, int K) {
  __shared__ __align__(16) bf16_t As[2][128 * 64];
  __shared__ __align__(16) bf16_t Bs[2][256 * 64];
  const int t = threadIdx.x;
  const int wid = t >> 6, l = t & 63;
  const int l15 = l & 15, l4 = l >> 4;
  const int wm = wid >> 2, wn = wid & 3;
  const long m0 = (long)blockIdx.x * 128;
  const long n0 = (long)blockIdx.y * 256;
  const int KT = K >> 6;

  auto stageA = [&](int kt, bf16_t* __restrict__ LB) {
    #pragma unroll
    for (int it = 0; it < 2; ++it) {
      int s = it * 512 + t;
      int r = s >> 3, c = s & 7;
      gload16(A + (m0 + r) * (long)K + kt * 64 + ((c ^ (r & 7)) << 3),
              LB + r * 64 + c * 8);
    }
  };
  auto stageB = [&](int kt, bf16_t* __restrict__ LB) {
    #pragma unroll
    for (int it = 0; it < 4; ++it) {
      int s = it * 512 + t;
      int r = s >> 3, c = s & 7;
      gload16(B + (n0 + r) * (long)K + kt * 64 + ((c ^ (r & 7)) << 3),
              LB + r * 64 + c * 8);
    }
  };
  auto ldfrag = [&](const bf16_t* buf, int rloc, int kk) -> bf16x8 {
    return *(const bf16x8*)(buf + rloc * 64 + ((((kk << 2) + l4) ^ (rloc & 7)) << 3));
  };

  f32x4 acc[4][4] = {};

  stageB(0, &Bs[0][0]);
  stageA(0, &As[0][0]);
  stageB(1, &Bs[1][0]);
  asm volatile("s_waitcnt vmcnt(4)" ::: "memory");
  asm volatile("s_barrier" ::: "memory");

  for (int kt = 0; kt < KT; ++kt) {
    const bf16_t* Ab = &As[kt & 1][0];
    const bf16_t* Bb = &Bs[kt & 1][0];
    const bool stA = (kt + 1 < KT), stB = (kt + 2 < KT);

    bf16x8 bfr[4][2];
    #pragma unroll
    for (int nr = 0; nr < 4; ++nr)
      #pragma unroll
      for (int kk = 0; kk < 2; ++kk)
        bfr[nr][kk] = ldfrag(Bb, wn * 64 + nr * 16 + l15, kk);
    {
      bf16x8 a00 = ldfrag(Ab, wm * 64 + 0 * 16 + l15, 0);
      bf16x8 a01 = ldfrag(Ab, wm * 64 + 0 * 16 + l15, 1);
      bf16x8 a10 = ldfrag(Ab, wm * 64 + 1 * 16 + l15, 0);
      bf16x8 a11 = ldfrag(Ab, wm * 64 + 1 * 16 + l15, 1);
      if (stA) stageA(kt + 1, &As[(kt + 1) & 1][0]);
      asm volatile("s_barrier" ::: "memory");
      __builtin_amdgcn_s_setprio(1);
      #pragma unroll
      for (int nr = 0; nr < 4; ++nr) {
        acc[0][nr] = mfma16(a00, bfr[nr][0], acc[0][nr]);
        acc[0][nr] = mfma16(a01, bfr[nr][1], acc[0][nr]);
        acc[1][nr] = mfma16(a10, bfr[nr][0], acc[1][nr]);
        acc[1][nr] = mfma16(a11, bfr[nr][1], acc[1][nr]);
      }
      __builtin_amdgcn_s_setprio(0);
      asm volatile("s_barrier" ::: "memory");
    }
    {
      bf16x8 a00 = ldfrag(Ab, wm * 64 + 2 * 16 + l15, 0);
      bf16x8 a01 = ldfrag(Ab, wm * 64 + 2 * 16 + l15, 1);
      bf16x8 a10 = ldfrag(Ab, wm * 64 + 3 * 16 + l15, 0);
      bf16x8 a11 = ldfrag(Ab, wm * 64 + 3 * 16 + l15, 1);
      if (stB) stageB(kt + 2, &Bs[kt & 1][0]);
      asm volatile("s_barrier" ::: "memory");
      __builtin_amdgcn_s_setprio(1);
      #pragma unroll
      for (int nr = 0; nr < 4; ++nr) {
        acc[2][nr] = mfma16(a00, bfr[nr][0], acc[2][nr]);
        acc[2][nr] = mfma16(a01, bfr[nr][1], acc[2][nr]);
        acc[3][nr] = mfma16(a10, bfr[nr][0], acc[3][nr]);
        acc[3][nr] = mfma16(a11, bfr[nr][1], acc[3][nr]);
      }
      __builtin_amdgcn_s_setprio(0);
      if (stB) asm volatile("s_waitcnt vmcnt(4)" ::: "memory");
      else     asm volatile("s_waitcnt vmcnt(0)" ::: "memory");
      asm volatile("s_barrier" ::: "memory");
    }
  }

  #pragma unroll
  for (int mr = 0; mr < 4; ++mr)
    #pragma unroll
    for (int nr = 0; nr < 4; ++nr)
      #pragma unroll
      for (int i = 0; i < 4; ++i) {
        long r = m0 + wm * 64 + mr * 16 + l4 * 4 + i;
        long c = n0 + wn * 64 + nr * 16 + l15;
        if (OUT_BF16) ((bf16_t*)Cout)[r * N + c] = (bf16_t)acc[mr][nr][i];
        else          ((float*)Cout)[r * N + c] = acc[mr][nr][i];
      }
}

// ---------------- causal flash attention v2: 256 q-rows/block ----------------
// Round-15 change: Q-block 128 -> 256 rows (1024 thr = 16 waves x 16 q-rows) to
// HALVE KV re-reads (attn moved ~278 MB ~= 4.5 TB/s -> KV-BW-bound). Grid 256 =
// 1 block/CU; LDS = Ks dbuf 32K + Vt dbuf 32K + Pb[16] 32K = 96 KiB; waves/SIMD
// unchanged (4). Per-wave structure identical to the round-12-verified kernel.
// Worst-CU tiles 32 (vs 34 paired before) -> no balance loss.
__global__ __launch_bounds__(1024, 4) void attn_causal(const bf16_t* __restrict__ qkv,
                                                       bf16_t* __restrict__ ao) {
  const int id = blockIdx.x;
  const int qt = 7 - (id >> 5);              // LPT: longest first
  const int bh = id & 31;
  const int b = bh >> 4, h = bh & 15;
  const int t = threadIdx.x;
  const int wid = t >> 6, l = t & 63;
  const int l15 = l & 15, l4 = l >> 4;
  __shared__ __align__(16) bf16_t Ks0[64 * 128];
  __shared__ __align__(16) bf16_t Ks1[64 * 128];
  __shared__ __align__(16) bf16_t Vt[2][128 * 64];
  __shared__ __align__(16) bf16_t Pb[16][16 * 64];
  const bf16_t* base = qkv + (long)b * 2048 * 6144 + h * 128;
  const int q0w = qt * 256 + wid * 16;
  bf16x8 qf[4];
  #pragma unroll
  for (int ks = 0; ks < 4; ++ks)
    qf[ks] = *(const bf16x8*)(base + (long)(q0w + l15) * 6144 + ks * 32 + l4 * 8);
  f32x4 o[8] = {};
  float mrun = -1.0e30f, lrun = 0.f;
  bf16_t* pbuf = Pb[wid];
  bf16x8 vr;
  const int ntiles = 4 * qt + 4;

  auto stageK = [&](int tile, bf16_t* dst) {
    const bf16_t* src = base + 2048 + (long)tile * 64 * 6144;
    int s = t;                               // 1024 chunks exactly
    int krow = s >> 4, kc = s & 15;
    int ksc = kc ^ (krow & 7);
    gload16(src + (long)krow * 6144 + ksc * 8, dst + (size_t)s * 8);
  };
  auto loadV = [&](int tile) {
    const bf16_t* vsr = base + 4096 + (long)(tile * 64 + l) * 6144;
    vr = *(const bf16x8*)(vsr + wid * 8);    // wave wid owns d-chunk wid
  };
  auto writeVt = [&](bf16_t* vt) {
    #pragma unroll
    for (int e = 0; e < 8; ++e) {
      int d = wid * 8 + e;                   // d&7 == e
      vt[d * 64 + (((l >> 3) ^ e) * 8) + (l & 7)] = vr[e];
    }
  };
  auto compute = [&](int kv0, const bf16_t* ksb, const bf16_t* vt) {
    if (kv0 > q0w + 15) return;
    f32x4 sa[4] = {};
    __builtin_amdgcn_s_setprio(1);
    #pragma unroll
    for (int ks = 0; ks < 4; ++ks) {
      #pragma unroll
      for (int nb = 0; nb < 4; ++nb) {
        int row = nb * 16 + l15;
        int cs = (ks * 4 + l4) ^ (row & 7);
        bf16x8 kf = *(const bf16x8*)(ksb + row * 128 + cs * 8);
        sa[nb] = mfma16(kf, qf[ks], sa[nb]);   // S^T: row=kv, col=q
      }
    }
    __builtin_amdgcn_s_setprio(0);
    if (kv0 + 63 > q0w) {
      const int q = q0w + l15;
      #pragma unroll
      for (int nb = 0; nb < 4; ++nb)
        #pragma unroll
        for (int i = 0; i < 4; ++i)
          if (kv0 + nb * 16 + l4 * 4 + i > q) sa[nb][i] = -3.0e38f;
    }
    f32x4 mv;
    #pragma unroll
    for (int i = 0; i < 4; ++i)
      mv[i] = fmaxf(fmaxf(sa[0][i], sa[1][i]), fmaxf(sa[2][i], sa[3][i]));
    float pmax = fmaxf(fmaxf(mv[0], mv[1]), fmaxf(mv[2], mv[3]));
    pmax = fmaxf(pmax, __shfl_xor(pmax, 16));
    pmax = fmaxf(pmax, __shfl_xor(pmax, 32));
    if (!__all(pmax - mrun <= 8.0f)) {
      float mnew = fmaxf(mrun, pmax);
      float corr = __expf(mrun - mnew);
      mrun = mnew;
      lrun *= corr;
      float cc[4];
      #pragma unroll
      for (int i = 0; i < 4; ++i) cc[i] = __shfl(corr, l4 * 4 + i);
      #pragma unroll
      for (int nf = 0; nf < 8; ++nf)
        #pragma unroll
        for (int i = 0; i < 4; ++i) o[nf][i] *= cc[i];
    }
    float ps = 0.f;
    #pragma unroll
    for (int nb = 0; nb < 4; ++nb)
      #pragma unroll
      for (int i = 0; i < 4; ++i) {
        float p = __expf(sa[nb][i] - mrun);
        sa[nb][i] = p;
        ps += p;
      }
    ps += __shfl_xor(ps, 16);
    ps += __shfl_xor(ps, 32);
    lrun += ps;
    #pragma unroll
    for (int nb = 0; nb < 4; ++nb) {
      int cw = (nb * 2 + (l4 >> 1)) ^ (l15 & 7);
      uint32_t* dst = (uint32_t*)(pbuf + l15 * 64 + cw * 8 + (l4 & 1) * 4);
      dst[0] = pack2(sa[nb][0], sa[nb][1]);
      dst[1] = pack2(sa[nb][2], sa[nb][3]);
    }
    #pragma unroll
    for (int ks2 = 0; ks2 < 2; ++ks2) {
      bf16x8 pf = *(const bf16x8*)(pbuf + l15 * 64 + (((ks2 * 4 + l4) ^ (l15 & 7)) * 8));
      __builtin_amdgcn_s_setprio(1);
      #pragma unroll
      for (int nf = 0; nf < 8; ++nf) {
        int row = nf * 16 + l15;
        bf16x8 vf = *(const bf16x8*)(vt + row * 64 + (((ks2 * 4 + l4) ^ (row & 7)) * 8));
        o[nf] = mfma16(pf, vf, o[nf]);
      }
      __builtin_amdgcn_s_setprio(0);
    }
  };

  stageK(0, Ks0);
  loadV(0);
  writeVt(Vt[0]);
  __syncthreads();
  for (int tile = 0; tile < ntiles; ++tile) {
    bf16_t* curK = (tile & 1) ? Ks1 : Ks0;
    bf16_t* nxtK = (tile & 1) ? Ks0 : Ks1;
    bf16_t* curV = Vt[tile & 1];
    bf16_t* nxtV = Vt[(tile + 1) & 1];
    const bool pre = (tile + 1 < ntiles);
    if (pre) { stageK(tile + 1, nxtK); loadV(tile + 1); }
    compute(tile * 64, curK, curV);
    if (pre) writeVt(nxtV);
    __syncthreads();
  }
  float linv = 1.f / lrun;
  float li[4];
  #pragma unroll
  for (int i = 0; i < 4; ++i) li[i] = __shfl(linv, l4 * 4 + i);
  bf16_t* aob = ao + (long)b * 2048 * 2048 + h * 128;
  #pragma unroll
  for (int i = 0; i < 4; ++i) {
    long qrow = q0w + l4 * 4 + i;
    #pragma unroll
    for (int nf = 0; nf < 8; ++nf)
      aob[qrow * 2048 + nf * 16 + l15] = (bf16_t)(o[nf][i] * li[i]);
  }
}

// ---------------- launch ----------------
extern "C" void kernel_launch(void* const* d_in, const int* in_sizes, int n_in,
                              void* d_out, int out_size, void* d_ws, size_t ws_size,
                              hipStream_t stream) {
  const float* x     = (const float*)d_in[0];
  const float* w_qkv = (const float*)d_in[1];
  const float* w_out = (const float*)d_in[2];
  char* ws = (char*)d_ws;
  bf16_t* xb    = (bf16_t*)(ws + 0L);           // 16 MiB  (4096x2048)
  bf16_t* wqkvb = (bf16_t*)(ws + 16777216L);    // 24 MiB  (6144x2048)
  bf16_t* woutb = (bf16_t*)(ws + 41943040L);    //  8 MiB  (2048x2048)
  bf16_t* qkv   = (bf16_t*)(ws + 50331648L);    // 48 MiB  (4096x6144)
  bf16_t* ao    = (bf16_t*)(ws + 100663296L);   // 16 MiB  (4096x2048) -> end 112 MiB

  cast_f32_to_bf16<<<2048, 256, 0, stream>>>(x, xb, 1048576);
  cast_f32_to_bf16<<<2048, 256, 0, stream>>>(w_qkv, wqkvb, 1572864);
  cast_f32_to_bf16<<<1024, 256, 0, stream>>>(w_out, woutb, 524288);
  // qkv[m][f] = sum_c x[m][c]*w_qkv[f][c], rope+scale fused in epilogue
  gemm_qkv<<<dim3(16, 16), 512, 0, stream>>>(xb, wqkvb, qkv, 4096, 6144, 2048);
  attn_causal<<<256, 1024, 0, stream>>>(qkv, ao);
  // out[m][c] = sum_f ao[m][f] * w_out[c][f]
  gemm8p_bt<false><<<dim3(32, 8), 512, 0, stream>>>(ao, woutb, d_out, 4096, 2048, 2048);
}

// Round 16
// 222.799 us; speedup vs baseline: 1.0757x; 1.0757x over previous
//
#include <hip/hip_runtime.h>
#include <hip/hip_bf16.h>
#include <stdint.h>

typedef __bf16 bf16_t;
typedef __bf16 bf16x8 __attribute__((ext_vector_type(8)));
typedef float  f32x4  __attribute__((ext_vector_type(4)));

__device__ __forceinline__ void gload16(const void* gp, void* lp) {
  __builtin_amdgcn_global_load_lds(
      (const __attribute__((address_space(1))) void*)(uintptr_t)gp,
      (__attribute__((address_space(3))) void*)(uintptr_t)lp,
      16, 0, 0);
}

__device__ __forceinline__ f32x4 mfma16(bf16x8 a, bf16x8 b, f32x4 c) {
  return __builtin_amdgcn_mfma_f32_16x16x32_bf16(a, b, c, 0, 0, 0);
}

__device__ __forceinline__ uint32_t pack2(float a, float b) {
  uint16_t ba = __builtin_bit_cast(uint16_t, (bf16_t)a);
  uint16_t bb = __builtin_bit_cast(uint16_t, (bf16_t)b);
  return (uint32_t)ba | ((uint32_t)bb << 16);
}

// ---------------- fused fp32 -> bf16 cast of x, w_qkv, w_out (one dispatch) ----------------
__global__ __launch_bounds__(256) void cast_all(const float* __restrict__ x,
                                                const float* __restrict__ wqkv,
                                                const float* __restrict__ wout,
                                                bf16_t* __restrict__ xb,
                                                bf16_t* __restrict__ wqkvb,
                                                bf16_t* __restrict__ woutb) {
  const int N1 = 1048576, N2 = 1572864, N3 = 524288;   // 8-elem chunks
  int i = blockIdx.x * 256 + threadIdx.x;
  int stride = gridDim.x * 256;
  for (; i < N1 + N2 + N3; i += stride) {
    const float* in; bf16_t* out; int j;
    if (i < N1)           { in = x;    out = xb;    j = i; }
    else if (i < N1 + N2) { in = wqkv; out = wqkvb; j = i - N1; }
    else                  { in = wout; out = woutb; j = i - N1 - N2; }
    const f32x4* p = (const f32x4*)in + (size_t)j * 2;
    f32x4 a = p[0], b = p[1];
    bf16x8 o;
    o[0] = (bf16_t)a[0]; o[1] = (bf16_t)a[1]; o[2] = (bf16_t)a[2]; o[3] = (bf16_t)a[3];
    o[4] = (bf16_t)b[0]; o[5] = (bf16_t)b[1]; o[6] = (bf16_t)b[2]; o[7] = (bf16_t)b[3];
    ((bf16x8*)out)[j] = o;
  }
}

// ======== 256x384 GEMM + fused RoPE/scale epilogue (gemm1) — round-13 verified ========
__global__ __launch_bounds__(512, 2) void gemm_qkv(const bf16_t* __restrict__ A,
                                                   const bf16_t* __restrict__ B,
                                                   bf16_t* __restrict__ C,
                                                   int M, int N, int K) {
  __shared__ __align__(16) bf16_t As[2][256 * 32];
  __shared__ __align__(16) bf16_t Bs[2][384 * 32];
  const int t = threadIdx.x;
  const int wid = t >> 6, l = t & 63;
  const int l15 = l & 15, l4 = l >> 4;
  const int wm = wid >> 2, wn = wid & 3;
  const long m0 = (long)blockIdx.x * 256;
  const long n0 = (long)blockIdx.y * 384;
  const int KT = K >> 5;

  auto stageA = [&](int kt, bf16_t* __restrict__ LB) {
    #pragma unroll
    for (int it = 0; it < 2; ++it) {
      int s = it * 512 + t;
      int r = s >> 2, c = s & 3;
      int cs = c ^ ((r >> 1) & 3);
      gload16(A + (m0 + r) * (long)K + kt * 32 + cs * 8, LB + r * 32 + c * 8);
    }
  };
  auto stageB = [&](int kt, bf16_t* __restrict__ LB) {
    #pragma unroll
    for (int it = 0; it < 3; ++it) {
      int s = it * 512 + t;
      int r = s >> 2, c = s & 3;
      int cs = c ^ ((r >> 1) & 3);
      gload16(B + (n0 + r) * (long)K + kt * 32 + cs * 8, LB + r * 32 + c * 8);
    }
  };
  auto ldfrag = [&](const bf16_t* buf, int rloc) -> bf16x8 {
    int cs = l4 ^ ((rloc >> 1) & 3);
    return *(const bf16x8*)(buf + rloc * 32 + cs * 8);
  };

  f32x4 acc[8][6] = {};

  stageB(0, &Bs[0][0]);
  stageA(0, &As[0][0]);
  stageB(1, &Bs[1][0]);
  asm volatile("s_waitcnt vmcnt(3)" ::: "memory");
  asm volatile("s_barrier" ::: "memory");

  for (int kt = 0; kt < KT; ++kt) {
    const bf16_t* Ab = &As[kt & 1][0];
    const bf16_t* Bb = &Bs[kt & 1][0];
    const bool stA = (kt + 1 < KT), stB = (kt + 2 < KT);

    bf16x8 bfr[6];
    #pragma unroll
    for (int nr = 0; nr < 6; ++nr) bfr[nr] = ldfrag(Bb, wn * 96 + nr * 16 + l15);
    {
      bf16x8 a0 = ldfrag(Ab, wm * 128 + 0 * 16 + l15);
      bf16x8 a1 = ldfrag(Ab, wm * 128 + 1 * 16 + l15);
      bf16x8 a2 = ldfrag(Ab, wm * 128 + 2 * 16 + l15);
      bf16x8 a3 = ldfrag(Ab, wm * 128 + 3 * 16 + l15);
      if (stA) stageA(kt + 1, &As[(kt + 1) & 1][0]);
      asm volatile("s_barrier" ::: "memory");
      __builtin_amdgcn_s_setprio(1);
      #pragma unroll
      for (int nr = 0; nr < 6; ++nr) {
        acc[0][nr] = mfma16(a0, bfr[nr], acc[0][nr]);
        acc[1][nr] = mfma16(a1, bfr[nr], acc[1][nr]);
        acc[2][nr] = mfma16(a2, bfr[nr], acc[2][nr]);
        acc[3][nr] = mfma16(a3, bfr[nr], acc[3][nr]);
      }
      __builtin_amdgcn_s_setprio(0);
      asm volatile("s_barrier" ::: "memory");
    }
    {
      bf16x8 a4 = ldfrag(Ab, wm * 128 + 4 * 16 + l15);
      bf16x8 a5 = ldfrag(Ab, wm * 128 + 5 * 16 + l15);
      bf16x8 a6 = ldfrag(Ab, wm * 128 + 6 * 16 + l15);
      bf16x8 a7 = ldfrag(Ab, wm * 128 + 7 * 16 + l15);
      if (stB) stageB(kt + 2, &Bs[kt & 1][0]);
      asm volatile("s_barrier" ::: "memory");
      __builtin_amdgcn_s_setprio(1);
      #pragma unroll
      for (int nr = 0; nr < 6; ++nr) {
        acc[4][nr] = mfma16(a4, bfr[nr], acc[4][nr]);
        acc[5][nr] = mfma16(a5, bfr[nr], acc[5][nr]);
        acc[6][nr] = mfma16(a6, bfr[nr], acc[6][nr]);
        acc[7][nr] = mfma16(a7, bfr[nr], acc[7][nr]);
      }
      __builtin_amdgcn_s_setprio(0);
      if (stB) asm volatile("s_waitcnt vmcnt(3)" ::: "memory");
      else     asm volatile("s_waitcnt vmcnt(0)" ::: "memory");
      asm volatile("s_barrier" ::: "memory");
    }
  }

  // ---- epilogue: fused rope(rot_dim=32) + q-scale (rule #20: static acc idx) ----
  const int nrA = ((128 - ((wn * 96) & 127)) & 127) >> 4;
  const float L2D16 = 0.8304820237218406f;
  const float invf = exp2f(-(float)l15 * L2D16);
  const float qscale = 0.08838834764831845f;
  const float INV2PI = 0.15915494309189535f;
  const float TWOPI  = 6.283185307179586f;
  const bool doRot = (nrA < 6) && ((n0 + wn * 96 + nrA * 16) < 4096);
  #pragma unroll
  for (int mr = 0; mr < 8; ++mr) {
    const long r0 = m0 + wm * 128 + mr * 16 + l4 * 4;
    if (doRot) {
      float sv[4], cv[4];
      #pragma unroll
      for (int i = 0; i < 4; ++i) {
        float ang = (float)((int)(r0 + i) & 2047) * invf;
        float rev = ang * INV2PI;
        rev -= floorf(rev);
        float r2 = rev * TWOPI;
        sv[i] = __sinf(r2);
        cv[i] = __cosf(r2);
      }
      #pragma unroll
      for (int nr = 0; nr < 5; ++nr) {
        if (nr == nrA) {
          #pragma unroll
          for (int i = 0; i < 4; ++i) {
            float a = acc[mr][nr][i], b2 = acc[mr][nr + 1][i];
            acc[mr][nr][i]     = a * cv[i] - b2 * sv[i];
            acc[mr][nr + 1][i] = b2 * cv[i] + a * sv[i];
          }
        }
      }
    }
    #pragma unroll
    for (int nr = 0; nr < 6; ++nr) {
      const long f0 = n0 + wn * 96 + nr * 16;
      if (f0 < 2048) {
        #pragma unroll
        for (int i = 0; i < 4; ++i) acc[mr][nr][i] *= qscale;
      }
      #pragma unroll
      for (int i = 0; i < 4; ++i)
        C[(r0 + i) * N + f0 + l15] = (bf16_t)acc[mr][nr][i];
    }
  }
}

// ======== 128x256 GEMM (gemm2), round-13 structure ========
template<bool OUT_BF16>
__global__ __launch_bounds__(512, 2) void gemm8p_bt(const bf16_t* __restrict__ A,
                                                    const bf16_t* __restrict__ B,
                                                    void* __restrict__ Cout,
                                                    int M, int N, int K) {
  __shared__ __align__(16) bf16_t As[2][128 * 64];
  __shared__ __align__(16) bf16_t Bs[2][256 * 64];
  const int t = threadIdx.x;
  const int wid = t >> 6, l = t & 63;
  const int l15 = l & 15, l4 = l >> 4;
  const int wm = wid >> 2, wn = wid & 3;
  const long m0 = (long)blockIdx.x * 128;
  const long n0 = (long)blockIdx.y * 256;
  const int KT = K >> 6;

  auto stageA = [&](int kt, bf16_t* __restrict__ LB) {
    #pragma unroll
    for (int it = 0; it < 2; ++it) {
      int s = it * 512 + t;
      int r = s >> 3, c = s & 7;
      gload16(A + (m0 + r) * (long)K + kt * 64 + ((c ^ (r & 7)) << 3),
              LB + r * 64 + c * 8);
    }
  };
  auto stageB = [&](int kt, bf16_t* __restrict__ LB) {
    #pragma unroll
    for (int it = 0; it < 4; ++it) {
      int s = it * 512 + t;
      int r = s >> 3, c = s & 7;
      gload16(B + (n0 + r) * (long)K + kt * 64 + ((c ^ (r & 7)) << 3),
              LB + r * 64 + c * 8);
    }
  };
  auto ldfrag = [&](const bf16_t* buf, int rloc, int kk) -> bf16x8 {
    return *(const bf16x8*)(buf + rloc * 64 + ((((kk << 2) + l4) ^ (rloc & 7)) << 3));
  };

  f32x4 acc[4][4] = {};

  stageB(0, &Bs[0][0]);
  stageA(0, &As[0][0]);
  stageB(1, &Bs[1][0]);
  asm volatile("s_waitcnt vmcnt(4)" ::: "memory");
  asm volatile("s_barrier" ::: "memory");

  for (int kt = 0; kt < KT; ++kt) {
    const bf16_t* Ab = &As[kt & 1][0];
    const bf16_t* Bb = &Bs[kt & 1][0];
    const bool stA = (kt + 1 < KT), stB = (kt + 2 < KT);

    bf16x8 bfr[4][2];
    #pragma unroll
    for (int nr = 0; nr < 4; ++nr)
      #pragma unroll
      for (int kk = 0; kk < 2; ++kk)
        bfr[nr][kk] = ldfrag(Bb, wn * 64 + nr * 16 + l15, kk);
    {
      bf16x8 a00 = ldfrag(Ab, wm * 64 + 0 * 16 + l15, 0);
      bf16x8 a01 = ldfrag(Ab, wm * 64 + 0 * 16 + l15, 1);
      bf16x8 a10 = ldfrag(Ab, wm * 64 + 1 * 16 + l15, 0);
      bf16x8 a11 = ldfrag(Ab, wm * 64 + 1 * 16 + l15, 1);
      if (stA) stageA(kt + 1, &As[(kt + 1) & 1][0]);
      asm volatile("s_barrier" ::: "memory");
      __builtin_amdgcn_s_setprio(1);
      #pragma unroll
      for (int nr = 0; nr < 4; ++nr) {
        acc[0][nr] = mfma16(a00, bfr[nr][0], acc[0][nr]);
        acc[0][nr] = mfma16(a01, bfr[nr][1], acc[0][nr]);
        acc[1][nr] = mfma16(a10, bfr[nr][0], acc[1][nr]);
        acc[1][nr] = mfma16(a11, bfr[nr][1], acc[1][nr]);
      }
      __builtin_amdgcn_s_setprio(0);
      asm volatile("s_barrier" ::: "memory");
    }
    {
      bf16x8 a00 = ldfrag(Ab, wm * 64 + 2 * 16 + l15, 0);
      bf16x8 a01 = ldfrag(Ab, wm * 64 + 2 * 16 + l15, 1);
      bf16x8 a10 = ldfrag(Ab, wm * 64 + 3 * 16 + l15, 0);
      bf16x8 a11 = ldfrag(Ab, wm * 64 + 3 * 16 + l15, 1);
      if (stB) stageB(kt + 2, &Bs[kt & 1][0]);
      asm volatile("s_barrier" ::: "memory");
      __builtin_amdgcn_s_setprio(1);
      #pragma unroll
      for (int nr = 0; nr < 4; ++nr) {
        acc[2][nr] = mfma16(a00, bfr[nr][0], acc[2][nr]);
        acc[2][nr] = mfma16(a01, bfr[nr][1], acc[2][nr]);
        acc[3][nr] = mfma16(a10, bfr[nr][0], acc[3][nr]);
        acc[3][nr] = mfma16(a11, bfr[nr][1], acc[3][nr]);
      }
      __builtin_amdgcn_s_setprio(0);
      if (stB) asm volatile("s_waitcnt vmcnt(4)" ::: "memory");
      else     asm volatile("s_waitcnt vmcnt(0)" ::: "memory");
      asm volatile("s_barrier" ::: "memory");
    }
  }

  #pragma unroll
  for (int mr = 0; mr < 4; ++mr)
    #pragma unroll
    for (int nr = 0; nr < 4; ++nr)
      #pragma unroll
      for (int i = 0; i < 4; ++i) {
        long r = m0 + wm * 64 + mr * 16 + l4 * 4 + i;
        long c = n0 + wn * 64 + nr * 16 + l15;
        if (OUT_BF16) ((bf16_t*)Cout)[r * N + c] = (bf16_t)acc[mr][nr][i];
        else          ((float*)Cout)[r * N + c] = acc[mr][nr][i];
      }
}

// ---------------- causal flash attention (round-12 verified: 128 q-rows, paired) ----------------
__global__ __launch_bounds__(512, 4) void attn_causal(const bf16_t* __restrict__ qkv,
                                                      bf16_t* __restrict__ ao) {
  const int id = blockIdx.x;
  const int qt = (id < 256) ? (15 - (id >> 5)) : ((id - 256) >> 5);
  const int bh = id & 31;
  const int b = bh >> 4, h = bh & 15;
  const int t = threadIdx.x;
  const int wid = t >> 6, l = t & 63;
  const int l15 = l & 15, l4 = l >> 4;
  __shared__ __align__(16) bf16_t Ks0[64 * 128];
  __shared__ __align__(16) bf16_t Ks1[64 * 128];
  __shared__ __align__(16) bf16_t Vt[2][128 * 64];
  __shared__ __align__(16) bf16_t Pb[8][16 * 64];
  const bf16_t* base = qkv + (long)b * 2048 * 6144 + h * 128;
  const int q0w = qt * 128 + wid * 16;
  bf16x8 qf[4];
  #pragma unroll
  for (int ks = 0; ks < 4; ++ks)
    qf[ks] = *(const bf16x8*)(base + (long)(q0w + l15) * 6144 + ks * 32 + l4 * 8);
  f32x4 o[8] = {};
  float mrun = -1.0e30f, lrun = 0.f;
  bf16_t* pbuf = Pb[wid];
  bf16x8 vr0, vr1;
  const int ntiles = 2 * qt + 2;

  auto stageK = [&](int tile, bf16_t* dst) {
    const bf16_t* src = base + 2048 + (long)tile * 64 * 6144;
    #pragma unroll
    for (int it = 0; it < 2; ++it) {
      int s = it * 512 + t;
      int krow = s >> 4, kc = s & 15;
      int ksc = kc ^ (krow & 7);
      gload16(src + (long)krow * 6144 + ksc * 8, dst + (size_t)s * 8);
    }
  };
  auto loadV = [&](int tile) {
    const bf16_t* vsr = base + 4096 + (long)(tile * 64 + l) * 6144;
    vr0 = *(const bf16x8*)(vsr + wid * 8);
    vr1 = *(const bf16x8*)(vsr + (8 + wid) * 8);
  };
  auto writeVt = [&](bf16_t* vt) {
    #pragma unroll
    for (int it = 0; it < 2; ++it) {
      int c = it * 8 + wid;
      bf16x8 v = it ? vr1 : vr0;
      #pragma unroll
      for (int e = 0; e < 8; ++e) {
        int d = c * 8 + e;
        vt[d * 64 + (((l >> 3) ^ e) * 8) + (l & 7)] = v[e];
      }
    }
  };
  auto compute = [&](int kv0, const bf16_t* ksb, const bf16_t* vt) {
    if (kv0 > q0w + 15) return;
    f32x4 sa[4] = {};
    __builtin_amdgcn_s_setprio(1);
    #pragma unroll
    for (int ks = 0; ks < 4; ++ks) {
      #pragma unroll
      for (int nb = 0; nb < 4; ++nb) {
        int row = nb * 16 + l15;
        int cs = (ks * 4 + l4) ^ (row & 7);
        bf16x8 kf = *(const bf16x8*)(ksb + row * 128 + cs * 8);
        sa[nb] = mfma16(kf, qf[ks], sa[nb]);   // S^T: row=kv, col=q
      }
    }
    __builtin_amdgcn_s_setprio(0);
    if (kv0 + 63 > q0w) {
      const int q = q0w + l15;
      #pragma unroll
      for (int nb = 0; nb < 4; ++nb)
        #pragma unroll
        for (int i = 0; i < 4; ++i)
          if (kv0 + nb * 16 + l4 * 4 + i > q) sa[nb][i] = -3.0e38f;
    }
    f32x4 mv;
    #pragma unroll
    for (int i = 0; i < 4; ++i)
      mv[i] = fmaxf(fmaxf(sa[0][i], sa[1][i]), fmaxf(sa[2][i], sa[3][i]));
    float pmax = fmaxf(fmaxf(mv[0], mv[1]), fmaxf(mv[2], mv[3]));
    pmax = fmaxf(pmax, __shfl_xor(pmax, 16));
    pmax = fmaxf(pmax, __shfl_xor(pmax, 32));
    if (!__all(pmax - mrun <= 8.0f)) {
      float mnew = fmaxf(mrun, pmax);
      float corr = __expf(mrun - mnew);
      mrun = mnew;
      lrun *= corr;
      float cc[4];
      #pragma unroll
      for (int i = 0; i < 4; ++i) cc[i] = __shfl(corr, l4 * 4 + i);
      #pragma unroll
      for (int nf = 0; nf < 8; ++nf)
        #pragma unroll
        for (int i = 0; i < 4; ++i) o[nf][i] *= cc[i];
    }
    float ps = 0.f;
    #pragma unroll
    for (int nb = 0; nb < 4; ++nb)
      #pragma unroll
      for (int i = 0; i < 4; ++i) {
        float p = __expf(sa[nb][i] - mrun);
        sa[nb][i] = p;
        ps += p;
      }
    ps += __shfl_xor(ps, 16);
    ps += __shfl_xor(ps, 32);
    lrun += ps;
    #pragma unroll
    for (int nb = 0; nb < 4; ++nb) {
      int cw = (nb * 2 + (l4 >> 1)) ^ (l15 & 7);
      uint32_t* dst = (uint32_t*)(pbuf + l15 * 64 + cw * 8 + (l4 & 1) * 4);
      dst[0] = pack2(sa[nb][0], sa[nb][1]);
      dst[1] = pack2(sa[nb][2], sa[nb][3]);
    }
    #pragma unroll
    for (int ks2 = 0; ks2 < 2; ++ks2) {
      bf16x8 pf = *(const bf16x8*)(pbuf + l15 * 64 + (((ks2 * 4 + l4) ^ (l15 & 7)) * 8));
      __builtin_amdgcn_s_setprio(1);
      #pragma unroll
      for (int nf = 0; nf < 8; ++nf) {
        int row = nf * 16 + l15;
        bf16x8 vf = *(const bf16x8*)(vt + row * 64 + (((ks2 * 4 + l4) ^ (row & 7)) * 8));
        o[nf] = mfma16(pf, vf, o[nf]);
      }
      __builtin_amdgcn_s_setprio(0);
    }
  };

  stageK(0, Ks0);
  loadV(0);
  writeVt(Vt[0]);
  __syncthreads();
  for (int tile = 0; tile < ntiles; ++tile) {
    bf16_t* curK = (tile & 1) ? Ks1 : Ks0;
    bf16_t* nxtK = (tile & 1) ? Ks0 : Ks1;
    bf16_t* curV = Vt[tile & 1];
    bf16_t* nxtV = Vt[(tile + 1) & 1];
    const bool pre = (tile + 1 < ntiles);
    if (pre) { stageK(tile + 1, nxtK); loadV(tile + 1); }
    compute(tile * 64, curK, curV);
    if (pre) writeVt(nxtV);
    __syncthreads();
  }
  float linv = 1.f / lrun;
  float li[4];
  #pragma unroll
  for (int i = 0; i < 4; ++i) li[i] = __shfl(linv, l4 * 4 + i);
  bf16_t* aob = ao + (long)b * 2048 * 2048 + h * 128;
  #pragma unroll
  for (int i = 0; i < 4; ++i) {
    long qrow = q0w + l4 * 4 + i;
    #pragma unroll
    for (int nf = 0; nf < 8; ++nf)
      aob[qrow * 2048 + nf * 16 + l15] = (bf16_t)(o[nf][i] * li[i]);
  }
}

// ---------------- launch ----------------
extern "C" void kernel_launch(void* const* d_in, const int* in_sizes, int n_in,
                              void* d_out, int out_size, void* d_ws, size_t ws_size,
                              hipStream_t stream) {
  const float* x     = (const float*)d_in[0];
  const float* w_qkv = (const float*)d_in[1];
  const float* w_out = (const float*)d_in[2];
  char* ws = (char*)d_ws;
  bf16_t* xb    = (bf16_t*)(ws + 0L);           // 16 MiB  (4096x2048)
  bf16_t* wqkvb = (bf16_t*)(ws + 16777216L);    // 24 MiB  (6144x2048)
  bf16_t* woutb = (bf16_t*)(ws + 41943040L);    //  8 MiB  (2048x2048)
  bf16_t* qkv   = (bf16_t*)(ws + 50331648L);    // 48 MiB  (4096x6144)
  bf16_t* ao    = (bf16_t*)(ws + 100663296L);   // 16 MiB  (4096x2048) -> end 112 MiB

  cast_all<<<2048, 256, 0, stream>>>(x, w_qkv, w_out, xb, wqkvb, woutb);
  // qkv[m][f] = sum_c x[m][c]*w_qkv[f][c], rope+scale fused in epilogue
  gemm_qkv<<<dim3(16, 16), 512, 0, stream>>>(xb, wqkvb, qkv, 4096, 6144, 2048);
  attn_causal<<<512, 512, 0, stream>>>(qkv, ao);
  // out[m][c] = sum_f ao[m][f] * w_out[c][f]
  gemm8p_bt<false><<<dim3(32, 8), 512, 0, stream>>>(ao, woutb, d_out, 4096, 2048, 2048);
}